// Round 7
// baseline (1479.485 us; speedup 1.0000x reference)
//
#include <hip/hip_runtime.h>
#include <math.h>

// Problem constants
#define Bn 256
#define Tn 100
#define In 1024
#define Hn 2048
#define On 10
#define Kc (In + Hn)   // 3072 concatenated K

typedef short s8v  __attribute__((ext_vector_type(8)));   // 8 x bf16 (as raw shorts), 4 VGPRs
typedef unsigned short us4 __attribute__((ext_vector_type(4)));
typedef float f32x4 __attribute__((ext_vector_type(4)));

__device__ __forceinline__ unsigned short f2bf(float f) {
    unsigned int u = __float_as_uint(f);
    u += 0x7fffu + ((u >> 16) & 1u);   // round-to-nearest-even
    return (unsigned short)(u >> 16);
}

// Branch-free exact tanh: 1 - 2/(exp(2x)+1). ~1e-6 abs err, under bf16 rounding.
__device__ __forceinline__ float fast_tanh(float x) {
    float e = __expf(x + x);
    return 1.0f - 2.0f * __builtin_amdgcn_rcpf(e + 1.0f);
}

// ---- setup kernels -------------------------------------------------------

// x [B][T][I] fp32 -> bf16, 4 elems/thread
__global__ void conv_x_kernel(const float4* __restrict__ src, ushort4* __restrict__ dst) {
    int i = blockIdx.x * 256 + threadIdx.x;
    float4 v = src[i];
    ushort4 o;
    o.x = f2bf(v.x); o.y = f2bf(v.y); o.z = f2bf(v.z); o.w = f2bf(v.w);
    dst[i] = o;
}

// src [K][N=2048] fp32 -> dst[n][colOff + k] bf16  (builds B^T = [Win;W]^T rows)
__global__ void transpose_bf16_kernel(const float* __restrict__ src, unsigned short* __restrict__ dst,
                                      int N, int ld, int colOff) {
    __shared__ float tile[32][33];
    int k0 = blockIdx.x * 32;
    int n0 = blockIdx.y * 32;
    int c = threadIdx.x & 31;
    int r = threadIdx.x >> 5;            // 0..7
    #pragma unroll
    for (int i = 0; i < 32; i += 8)
        tile[r + i][c] = src[(size_t)(k0 + r + i) * N + n0 + c];
    __syncthreads();
    #pragma unroll
    for (int i = 0; i < 32; i += 8)
        dst[(size_t)(n0 + r + i) * ld + colOff + k0 + c] = f2bf(tile[c][r + i]);
}

// h0 -> h_all slot 0 (bf16); lin_w -> padded bf16 [16][2048]; zero barrier block
__global__ void small_conv_kernel(const float* __restrict__ h0, const float* __restrict__ lin_w,
                                  unsigned short* __restrict__ h_all0, unsigned short* __restrict__ lwb,
                                  unsigned int* __restrict__ bar) {
    int idx = blockIdx.x * 256 + threadIdx.x;
    if (idx < 512) bar[idx] = 0u;        // per-block flags (re-zeroed every launch)
    if (idx < Bn * Hn) {
        h_all0[idx] = f2bf(h0[idx]);
    } else {
        int j = idx - Bn * Hn;           // < 16*2048 exactly (grid sized for it)
        int o = j >> 11;
        int k = j & 2047;
        lwb[j] = (o < On) ? f2bf(lin_w[o * Hn + k]) : (unsigned short)0;
    }
}

// ---- persistent scan -----------------------------------------------------
// R11 = R10 skeleton (8 waves = 2/SIMD, XCD-pair-pinned m-groups, k-chunk
// rotation, flag barrier, w0-poll, lgkm-only sync1, 8-slab reduce)
// + DEPTH-4 h RING funded by de-persisting bx.
// R10 post-mortem: step 11.7us = ~1.3 MFMA + ~0.9 VALU + ~2.8 L2-service
// (32 blocks/XCD re-read the same 256KB h + 128KB x slab every step) +
// exposed h-load latency + sync. The depth-2 ring covers ~90cy of a ~700cy
// RTT -> ~1.5-2us/step exposed (why R9's HBM->L2 move was a null: the
// DEPTH, not the SOURCE, is the problem; L2-miss->L3 RTT ~ HBM RTT).
// R11 changes:
//  * bx NO LONGER PERSISTENT (was 32 AGPR): re-loaded each step inside the
//    x-part (addresses constant -> L1/L2-hot; loads don't depend on the
//    barrier -> off-chain). Unified budget 2w/SIMD = 256: R10 was 108+128;
//    now ~140 arch + 96 AGPR (bh 64 + acc 32) = ~236.
//  * DEPTH-4 h RING (A[4][4], 64 VGPR): prologue issues 16 loads; chunk
//    c+4 reloads slot c&3 right after c's MFMAs -> lead ~3 chunks (~270cy)
//    vs ~90cy. Halves exposed h latency.
// Sync (proven R4-R10): relaxed agent-scope write-through h stores;
// __syncthreads (sync2) drains vmcnt(0) before the flag store; per-block
// flag; w0-only poll + raw-barrier release; fresh h addresses each step
// make plain consumer loads safe.
__global__ __launch_bounds__(512, 2)
void scan_kernel(const unsigned short* __restrict__ xb,
                 const unsigned short* __restrict__ BTm,
                 unsigned short* __restrict__ h_all,
                 unsigned int* __restrict__ bar) {
    const int g = blockIdx.x;
    const int mg = (g & 7) >> 1;                        // m-group = XCD pair
    const int m0 = mg * 64;
    const int nIdx = (g >> 3) * 2 + (g & 1);            // 0..63 within group
    const int n0 = nIdx * 32;
    const int w = threadIdx.x >> 6;                     // 0..7
    const int lane = threadIdx.x & 63;
    const int quad = lane >> 4;
    const int lr = lane & 15;
    const int hoff = nIdx & 7;                          // h k-rotation
    const int xoff = nIdx & 3;                          // x k-rotation

    __shared__ float red[8][64][36];                    // pad 36: 2-way banks (free)

    const unsigned short* bp0 = BTm + (size_t)(n0 + lr) * Kc;
    const unsigned short* bp1 = BTm + (size_t)(n0 + 16 + lr) * Kc;

    const size_t xrow = (size_t)Tn * In;                // x row stride (102400)

    // flag layout: bar[mg*64 + (g&1)*32 + (g>>3)]  (bijective per group)
    const int fidx = mg * 64 + (g & 1) * 32 + (g >> 3);
    unsigned int* fl = bar + mg * 64;                   // my group's 64 flags

    // ---- one-time bh preload (persistent AGPR, all 100 steps) ----
    s8v bh[8][2];                                       // bh[c] = h-chunk (c+hoff)&7
    #pragma unroll
    for (int c = 0; c < 8; ++c) {
        const int kq = In + w * 256 + (((c + hoff) & 7) * 32) + quad * 8;
        bh[c][0] = *(const s8v*)(bp0 + kq);
        bh[c][1] = *(const s8v*)(bp1 + kq);
    }

    f32x4 acc[4][2];
    #pragma unroll
    for (int mi = 0; mi < 4; ++mi)
        #pragma unroll
        for (int ni = 0; ni < 2; ++ni)
            acc[mi][ni] = (f32x4){0.f, 0.f, 0.f, 0.f};

    // ---- x-part for t=0 (bx transient; all loads upfront) ----
    {
        s8v bx0[4], bx1[4];
        #pragma unroll
        for (int c = 0; c < 4; ++c) {
            const int kq = w * 128 + (((c + xoff) & 3) * 32) + quad * 8;
            bx0[c] = *(const s8v*)(bp0 + kq);
            bx1[c] = *(const s8v*)(bp1 + kq);
        }
        const unsigned short* ar0 = xb + (size_t)(m0 + lr) * xrow + w * 128 + quad * 8;
        s8v X[4][4];
        #pragma unroll
        for (int c = 0; c < 4; ++c)
            #pragma unroll
            for (int r = 0; r < 4; ++r)
                X[c][r] = *(const s8v*)(ar0 + ((c + xoff) & 3) * 32 + r * 16 * xrow);
        #pragma unroll
        for (int c = 0; c < 4; ++c) {
            acc[0][0] = __builtin_amdgcn_mfma_f32_16x16x32_bf16(X[c][0], bx0[c], acc[0][0], 0, 0, 0);
            acc[1][0] = __builtin_amdgcn_mfma_f32_16x16x32_bf16(X[c][1], bx0[c], acc[1][0], 0, 0, 0);
            acc[2][0] = __builtin_amdgcn_mfma_f32_16x16x32_bf16(X[c][2], bx0[c], acc[2][0], 0, 0, 0);
            acc[3][0] = __builtin_amdgcn_mfma_f32_16x16x32_bf16(X[c][3], bx0[c], acc[3][0], 0, 0, 0);
            acc[0][1] = __builtin_amdgcn_mfma_f32_16x16x32_bf16(X[c][0], bx1[c], acc[0][1], 0, 0, 0);
            acc[1][1] = __builtin_amdgcn_mfma_f32_16x16x32_bf16(X[c][1], bx1[c], acc[1][1], 0, 0, 0);
            acc[2][1] = __builtin_amdgcn_mfma_f32_16x16x32_bf16(X[c][2], bx1[c], acc[2][1], 0, 0, 0);
            acc[3][1] = __builtin_amdgcn_mfma_f32_16x16x32_bf16(X[c][3], bx1[c], acc[3][1], 0, 0, 0);
        }
    }

    for (int t = 0; t < Tn; ++t) {
        // ---- h-part: depth-4 ring (16 loads in flight; reload-after-use) ----
        const unsigned short* hrow = h_all + (size_t)t * (Bn * Hn)
                                   + (size_t)(m0 + lr) * Hn + w * 256 + quad * 8;
        s8v A[4][4];
        #pragma unroll
        for (int c = 0; c < 4; ++c)
            #pragma unroll
            for (int r = 0; r < 4; ++r)
                A[c][r] = *(const s8v*)(hrow + ((c + hoff) & 7) * 32 + r * 16 * Hn);
        #pragma unroll
        for (int c = 0; c < 8; ++c) {
            const s8v a0 = A[c & 3][0];
            const s8v a1 = A[c & 3][1];
            const s8v a2 = A[c & 3][2];
            const s8v a3 = A[c & 3][3];
            acc[0][0] = __builtin_amdgcn_mfma_f32_16x16x32_bf16(a0, bh[c][0], acc[0][0], 0, 0, 0);
            acc[1][0] = __builtin_amdgcn_mfma_f32_16x16x32_bf16(a1, bh[c][0], acc[1][0], 0, 0, 0);
            acc[2][0] = __builtin_amdgcn_mfma_f32_16x16x32_bf16(a2, bh[c][0], acc[2][0], 0, 0, 0);
            acc[3][0] = __builtin_amdgcn_mfma_f32_16x16x32_bf16(a3, bh[c][0], acc[3][0], 0, 0, 0);
            acc[0][1] = __builtin_amdgcn_mfma_f32_16x16x32_bf16(a0, bh[c][1], acc[0][1], 0, 0, 0);
            acc[1][1] = __builtin_amdgcn_mfma_f32_16x16x32_bf16(a1, bh[c][1], acc[1][1], 0, 0, 0);
            acc[2][1] = __builtin_amdgcn_mfma_f32_16x16x32_bf16(a2, bh[c][1], acc[2][1], 0, 0, 0);
            acc[3][1] = __builtin_amdgcn_mfma_f32_16x16x32_bf16(a3, bh[c][1], acc[3][1], 0, 0, 0);
            if (c < 4) {                                 // reload slot with chunk c+4
                #pragma unroll
                for (int r = 0; r < 4; ++r)
                    A[c & 3][r] = *(const s8v*)(hrow + ((c + 4 + hoff) & 7) * 32 + r * 16 * Hn);
            }
        }

        // ---- LDS reduce write: C/D layout row=quad*4+reg, col=lane&15 ----
        #pragma unroll
        for (int mi = 0; mi < 4; ++mi)
            #pragma unroll
            for (int ni = 0; ni < 2; ++ni)
                #pragma unroll
                for (int rr = 0; rr < 4; ++rr)
                    red[w][mi * 16 + quad * 4 + rr][ni * 16 + lr] = acc[mi][ni][rr];

        // ---- x-prefetch (2 of 4 chunks) for t+1: flies under the reduce ----
        s8v X[2][4];
        const unsigned short* arn = xb + (size_t)(t + 1) * In
                                  + (size_t)(m0 + lr) * xrow + w * 128 + quad * 8;
        if (t < Tn - 1) {
            #pragma unroll
            for (int c = 0; c < 2; ++c) {
                const unsigned short* p = arn + ((c + xoff) & 3) * 32;
                #pragma unroll
                for (int r = 0; r < 4; ++r)
                    X[c][r] = *(const s8v*)(p + r * 16 * xrow);
            }
        }

        // sync1: LDS-only barrier (NO vmcnt drain -> X stays in flight)
        __builtin_amdgcn_sched_barrier(0);
        asm volatile("s_waitcnt lgkmcnt(0)" ::: "memory");
        __builtin_amdgcn_s_barrier();
        __builtin_amdgcn_sched_barrier(0);

        {   // final reduce + tanh + agent-scope write-through store (8 B)
            int j = threadIdx.x << 2;
            int row = j >> 5;
            int c0 = j & 31;
            float4 s0 = *(const float4*)&red[0][row][c0];
            float4 s1 = *(const float4*)&red[1][row][c0];
            float4 s2 = *(const float4*)&red[2][row][c0];
            float4 s3 = *(const float4*)&red[3][row][c0];
            float4 s4 = *(const float4*)&red[4][row][c0];
            float4 s5 = *(const float4*)&red[5][row][c0];
            float4 s6 = *(const float4*)&red[6][row][c0];
            float4 s7 = *(const float4*)&red[7][row][c0];
            us4 o4;
            o4[0] = f2bf(fast_tanh(((s0.x + s1.x) + (s2.x + s3.x)) + ((s4.x + s5.x) + (s6.x + s7.x))));
            o4[1] = f2bf(fast_tanh(((s0.y + s1.y) + (s2.y + s3.y)) + ((s4.y + s5.y) + (s6.y + s7.y))));
            o4[2] = f2bf(fast_tanh(((s0.z + s1.z) + (s2.z + s3.z)) + ((s4.z + s5.z) + (s6.z + s7.z))));
            o4[3] = f2bf(fast_tanh(((s0.w + s1.w) + (s2.w + s3.w)) + ((s4.w + s5.w) + (s6.w + s7.w))));
            unsigned long long* dst = (unsigned long long*)
                (h_all + (size_t)(t + 1) * (Bn * Hn) + (size_t)(m0 + row) * Hn + n0 + c0);
            __hip_atomic_store(dst, __builtin_bit_cast(unsigned long long, o4),
                               __ATOMIC_RELAXED, __HIP_MEMORY_SCOPE_AGENT);
        }

        if (t < Tn - 1) {
            __syncthreads();                             // sync2: vmcnt(0) drain (h store; X done)
            const unsigned int tp1 = (unsigned int)(t + 1);

            // ---- ARRIVE: one contention-free flag store ----
            if (threadIdx.x == 0)
                __hip_atomic_store(bar + fidx, tp1, __ATOMIC_RELAXED,
                                   __HIP_MEMORY_SCOPE_AGENT);

            // ---- x-part of t+1: bx loads + chunk-2,3 loads issued FIRST ----
            s8v bx0[4], bx1[4];
            #pragma unroll
            for (int c = 0; c < 4; ++c) {
                const int kq = w * 128 + (((c + xoff) & 3) * 32) + quad * 8;
                bx0[c] = *(const s8v*)(bp0 + kq);
                bx1[c] = *(const s8v*)(bp1 + kq);
            }
            s8v X2[2][4];
            #pragma unroll
            for (int c = 0; c < 2; ++c) {
                const unsigned short* p = arn + ((c + 2 + xoff) & 3) * 32;
                #pragma unroll
                for (int r = 0; r < 4; ++r)
                    X2[c][r] = *(const s8v*)(p + r * 16 * xrow);
            }
            #pragma unroll
            for (int mi = 0; mi < 4; ++mi)
                #pragma unroll
                for (int ni = 0; ni < 2; ++ni)
                    acc[mi][ni] = (f32x4){0.f, 0.f, 0.f, 0.f};
            #pragma unroll
            for (int c = 0; c < 2; ++c) {
                acc[0][0] = __builtin_amdgcn_mfma_f32_16x16x32_bf16(X[c][0], bx0[c], acc[0][0], 0, 0, 0);
                acc[1][0] = __builtin_amdgcn_mfma_f32_16x16x32_bf16(X[c][1], bx0[c], acc[1][0], 0, 0, 0);
                acc[2][0] = __builtin_amdgcn_mfma_f32_16x16x32_bf16(X[c][2], bx0[c], acc[2][0], 0, 0, 0);
                acc[3][0] = __builtin_amdgcn_mfma_f32_16x16x32_bf16(X[c][3], bx0[c], acc[3][0], 0, 0, 0);
                acc[0][1] = __builtin_amdgcn_mfma_f32_16x16x32_bf16(X[c][0], bx1[c], acc[0][1], 0, 0, 0);
                acc[1][1] = __builtin_amdgcn_mfma_f32_16x16x32_bf16(X[c][1], bx1[c], acc[1][1], 0, 0, 0);
                acc[2][1] = __builtin_amdgcn_mfma_f32_16x16x32_bf16(X[c][2], bx1[c], acc[2][1], 0, 0, 0);
                acc[3][1] = __builtin_amdgcn_mfma_f32_16x16x32_bf16(X[c][3], bx1[c], acc[3][1], 0, 0, 0);
            }
            #pragma unroll
            for (int c = 0; c < 2; ++c) {
                acc[0][0] = __builtin_amdgcn_mfma_f32_16x16x32_bf16(X2[c][0], bx0[c + 2], acc[0][0], 0, 0, 0);
                acc[1][0] = __builtin_amdgcn_mfma_f32_16x16x32_bf16(X2[c][1], bx0[c + 2], acc[1][0], 0, 0, 0);
                acc[2][0] = __builtin_amdgcn_mfma_f32_16x16x32_bf16(X2[c][2], bx0[c + 2], acc[2][0], 0, 0, 0);
                acc[3][0] = __builtin_amdgcn_mfma_f32_16x16x32_bf16(X2[c][3], bx0[c + 2], acc[3][0], 0, 0, 0);
                acc[0][1] = __builtin_amdgcn_mfma_f32_16x16x32_bf16(X2[c][0], bx1[c + 2], acc[0][1], 0, 0, 0);
                acc[1][1] = __builtin_amdgcn_mfma_f32_16x16x32_bf16(X2[c][1], bx1[c + 2], acc[1][1], 0, 0, 0);
                acc[2][1] = __builtin_amdgcn_mfma_f32_16x16x32_bf16(X2[c][2], bx1[c + 2], acc[2][1], 0, 0, 0);
                acc[3][1] = __builtin_amdgcn_mfma_f32_16x16x32_bf16(X2[c][3], bx1[c + 2], acc[3][1], 0, 0, 0);
            }

            // ---- w0-only poll + raw-barrier release ----
            if (w == 0) {
                while (true) {
                    unsigned int v = __hip_atomic_load(fl + lane, __ATOMIC_RELAXED,
                                                       __HIP_MEMORY_SCOPE_AGENT);
                    if (__all((int)(v >= tp1))) break;
                    __builtin_amdgcn_s_sleep(1);
                }
            }
            asm volatile("" ::: "memory");
            __builtin_amdgcn_s_barrier();                // sync3: release all waves
            __builtin_amdgcn_sched_barrier(0);
        }
    }
}

// ---- output projection ---------------------------------------------------
// y[b][t][o] = h_all[t+1][b][:] . lin_w[o][:] + lin_b[o]. One 16-row wave per 16 (t,b) rows.
__global__ __launch_bounds__(256)
void gemm2_kernel(const unsigned short* __restrict__ h_all, const unsigned short* __restrict__ lwb,
                  const float* __restrict__ lb, float* __restrict__ y) {
    int gw = blockIdx.x * 4 + (threadIdx.x >> 6);       // 0..1599
    int lane = threadIdx.x & 63, quad = lane >> 4, lr = lane & 15;
    int m0 = gw * 16;
    int t = m0 >> 8;
    int b0 = m0 & 255;
    const unsigned short* ah = h_all + ((size_t)(t + 1) * Bn + b0 + lr) * Hn + quad * 8;
    const unsigned short* bh = lwb + (size_t)lr * Hn + quad * 8;
    f32x4 acc0 = {0.f, 0.f, 0.f, 0.f}, acc1 = {0.f, 0.f, 0.f, 0.f};
    #pragma unroll
    for (int k0 = 0; k0 < Hn; k0 += 64) {
        s8v a0 = *(const s8v*)(ah + k0);
        s8v b0 = *(const s8v*)(bh + k0);
        acc0 = __builtin_amdgcn_mfma_f32_16x16x32_bf16(a0, b0, acc0, 0, 0, 0);
        s8v a1 = *(const s8v*)(ah + k0 + 32);
        s8v b1 = *(const s8v*)(bh + k0 + 32);
        acc1 = __builtin_amdgcn_mfma_f32_16x16x32_bf16(a1, b1, acc1, 0, 0, 0);
    }
    acc0 = acc0 + acc1;
    if (lr < On) {
        float bias = lb[lr];
        #pragma unroll
        for (int rr = 0; rr < 4; ++rr) {
            int b = b0 + quad * 4 + rr;
            y[(size_t)b * (Tn * On) + t * On + lr] = acc0[rr] + bias;
        }
    }
}

// ---- host ----------------------------------------------------------------

extern "C" void kernel_launch(void* const* d_in, const int* in_sizes, int n_in,
                              void* d_out, int out_size, void* d_ws, size_t ws_size,
                              hipStream_t stream) {
    const float* x   = (const float*)d_in[0];
    const float* h0  = (const float*)d_in[1];
    const float* Win = (const float*)d_in[2];
    const float* W   = (const float*)d_in[3];
    const float* lw  = (const float*)d_in[4];
    const float* lb  = (const float*)d_in[5];
    float* y = (float*)d_out;

    // ws layout (bf16 elems): ~171 MB total
    unsigned short* ws    = (unsigned short*)d_ws;
    unsigned short* xb    = ws;                                  // 26,214,400 elems
    unsigned short* BTm   = xb + (size_t)Bn * Tn * In;           //  6,291,456 elems [2048][3072]
    unsigned short* h_all = BTm + (size_t)Hn * Kc;               // 52,953,088 elems [(T+1)][B][H]
    unsigned short* lwb   = h_all + (size_t)(Tn + 1) * Bn * Hn;  //     32,768 elems [16][2048]
    unsigned int*   bar   = (unsigned int*)(lwb + 32768);        // 512 uints flag block

    conv_x_kernel<<<25600, 256, 0, stream>>>((const float4*)x, (ushort4*)xb);
    transpose_bf16_kernel<<<dim3(32, 64), 256, 0, stream>>>(Win, BTm, Hn, Kc, 0);
    transpose_bf16_kernel<<<dim3(64, 64), 256, 0, stream>>>(W, BTm, Hn, Kc, In);
    small_conv_kernel<<<2176, 256, 0, stream>>>(h0, lw, h_all, lwb, bar);

    scan_kernel<<<256, 512, 0, stream>>>(xb, BTm, h_all, bar);

    gemm2_kernel<<<400, 256, 0, stream>>>(h_all, lwb, lb, y);
}

// Round 9
// 1312.342 us; speedup vs baseline: 1.1274x; 1.1274x over previous
//
#include <hip/hip_runtime.h>
#include <math.h>

// Problem constants
#define Bn 256
#define Tn 100
#define In 1024
#define Hn 2048
#define On 10
#define Kc (In + Hn)   // 3072 concatenated K

typedef short s8v  __attribute__((ext_vector_type(8)));   // 8 x bf16 (as raw shorts), 4 VGPRs
typedef unsigned short us4 __attribute__((ext_vector_type(4)));
typedef float f32x4 __attribute__((ext_vector_type(4)));

__device__ __forceinline__ unsigned short f2bf(float f) {
    unsigned int u = __float_as_uint(f);
    u += 0x7fffu + ((u >> 16) & 1u);   // round-to-nearest-even
    return (unsigned short)(u >> 16);
}

// Branch-free exact tanh: 1 - 2/(exp(2x)+1). ~1e-6 abs err, under bf16 rounding.
__device__ __forceinline__ float fast_tanh(float x) {
    float e = __expf(x + x);
    return 1.0f - 2.0f * __builtin_amdgcn_rcpf(e + 1.0f);
}

// ---- setup kernels -------------------------------------------------------

// x [B][T][I] fp32 -> bf16, 4 elems/thread
__global__ void conv_x_kernel(const float4* __restrict__ src, ushort4* __restrict__ dst) {
    int i = blockIdx.x * 256 + threadIdx.x;
    float4 v = src[i];
    ushort4 o;
    o.x = f2bf(v.x); o.y = f2bf(v.y); o.z = f2bf(v.z); o.w = f2bf(v.w);
    dst[i] = o;
}

// src [K][N=2048] fp32 -> dst[n][colOff + k] bf16  (builds B^T = [Win;W]^T rows)
__global__ void transpose_bf16_kernel(const float* __restrict__ src, unsigned short* __restrict__ dst,
                                      int N, int ld, int colOff) {
    __shared__ float tile[32][33];
    int k0 = blockIdx.x * 32;
    int n0 = blockIdx.y * 32;
    int c = threadIdx.x & 31;
    int r = threadIdx.x >> 5;            // 0..7
    #pragma unroll
    for (int i = 0; i < 32; i += 8)
        tile[r + i][c] = src[(size_t)(k0 + r + i) * N + n0 + c];
    __syncthreads();
    #pragma unroll
    for (int i = 0; i < 32; i += 8)
        dst[(size_t)(n0 + r + i) * ld + colOff + k0 + c] = f2bf(tile[c][r + i]);
}

// h0 -> h_all slot 0 (bf16); lin_w -> padded bf16 [16][2048]; zero barrier block
__global__ void small_conv_kernel(const float* __restrict__ h0, const float* __restrict__ lin_w,
                                  unsigned short* __restrict__ h_all0, unsigned short* __restrict__ lwb,
                                  unsigned int* __restrict__ bar) {
    int idx = blockIdx.x * 256 + threadIdx.x;
    if (idx < 512) bar[idx] = 0u;        // per-block flags (re-zeroed every launch)
    if (idx < Bn * Hn) {
        h_all0[idx] = f2bf(h0[idx]);
    } else {
        int j = idx - Bn * Hn;           // < 16*2048 exactly (grid sized for it)
        int o = j >> 11;
        int k = j & 2047;
        lwb[j] = (o < On) ? f2bf(lin_w[o * Hn + k]) : (unsigned short)0;
    }
}

// ---- persistent scan -----------------------------------------------------
// R13 = R10 base (proven 1174us: 8 waves = 2/SIMD, XCD-pair-pinned m-groups,
// k-chunk rotation, depth-2 h ring, bx persistent, flag barrier, 8-slab
// reduce, lgkm-only sync1, x-prefetch under reduce) + PER-WAVE PRODUCER POLL.
// R12 post-mortem (FAILED correctness): the counted-vmcnt flag-early trick
// assumed the h-store issues before the X loads; the store is a RELAXED
// atomic, so LLVM may reorder plain loads ahead of it -> vmcnt(8) retired a
// load, flag published before h was visible, consumers read stale h. Only
// vmcnt(0) (i.e. __syncthreads) is compiler-proof at HIP level. Dropped.
// KEPT from R12 (orthogonal to store visibility): per-wave dataflow release.
//  * Wave w's h k-slice [w*256,+256) is produced by exactly blocks
//    nIdx in [w*8, w*8+8). Each wave polls only ITS 8 producer flags
//    (fl[w*8+(lane&7)], __all); sync3 release barrier deleted. A wave
//    starts its h-loads the moment its own producers are visible instead
//    of the max over all 64 blocks + a block-wide re-convergence.
//  * LDS-safe: all red reads complete before sync2 (barrier); each wave
//    writes only red[w] after passing sync2; block re-converges at sync1.
// Sync (proven R4-R10): relaxed agent-scope write-through h stores;
// __syncthreads (sync2) drains vmcnt(0) before the flag store; fresh h
// addresses each step make plain consumer loads safe.
__global__ __launch_bounds__(512, 2)
void scan_kernel(const unsigned short* __restrict__ xb,
                 const unsigned short* __restrict__ BTm,
                 unsigned short* __restrict__ h_all,
                 unsigned int* __restrict__ bar) {
    const int g = blockIdx.x;
    const int mg = (g & 7) >> 1;                        // m-group = XCD pair
    const int m0 = mg * 64;
    const int nIdx = (g >> 3) * 2 + (g & 1);            // 0..63 within group
    const int n0 = nIdx * 32;
    const int w = threadIdx.x >> 6;                     // 0..7
    const int lane = threadIdx.x & 63;
    const int quad = lane >> 4;
    const int lr = lane & 15;
    const int hoff = nIdx & 7;                          // h k-rotation
    const int xoff = nIdx & 3;                          // x k-rotation

    __shared__ float red[8][64][36];                    // pad 36: 2-way banks (free)

    const unsigned short* bp0 = BTm + (size_t)(n0 + lr) * Kc;
    const unsigned short* bp1 = BTm + (size_t)(n0 + 16 + lr) * Kc;

    const size_t xrow = (size_t)Tn * In;                // x row stride (102400)

    // flag layout: bar[mg*64 + (g&1)*32 + (g>>3)]  (bijective per group)
    const int fidx = mg * 64 + (g & 1) * 32 + (g >> 3);
    unsigned int* fl = bar + mg * 64;                   // my group's 64 flags

    // ---- one-time B-fragment preload, PRE-ROTATED by hoff/xoff ----
    s8v bx[4][2];                                       // bx[c] = x-chunk (c+xoff)&3
    s8v bh[8][2];                                       // bh[c] = h-chunk (c+hoff)&7
    #pragma unroll
    for (int c = 0; c < 4; ++c) {
        const int kq = w * 128 + (((c + xoff) & 3) * 32) + quad * 8;
        bx[c][0] = *(const s8v*)(bp0 + kq);
        bx[c][1] = *(const s8v*)(bp1 + kq);
    }
    #pragma unroll
    for (int c = 0; c < 8; ++c) {
        const int kq = In + w * 256 + (((c + hoff) & 7) * 32) + quad * 8;
        bh[c][0] = *(const s8v*)(bp0 + kq);
        bh[c][1] = *(const s8v*)(bp1 + kq);
    }

    f32x4 acc[4][2];
    #pragma unroll
    for (int mi = 0; mi < 4; ++mi)
        #pragma unroll
        for (int ni = 0; ni < 2; ++ni)
            acc[mi][ni] = (f32x4){0.f, 0.f, 0.f, 0.f};

    // ---- x-part for t=0 (rotated chunk order) ----
    {
        const unsigned short* ar0 = xb + (size_t)(m0 + lr) * xrow + w * 128 + quad * 8;
        #pragma unroll
        for (int c = 0; c < 4; ++c) {
            const unsigned short* arow = ar0 + ((c + xoff) & 3) * 32;
            s8v a0 = *(const s8v*)(arow);
            s8v a1 = *(const s8v*)(arow + 16 * xrow);
            s8v a2 = *(const s8v*)(arow + 32 * xrow);
            s8v a3 = *(const s8v*)(arow + 48 * xrow);
            acc[0][0] = __builtin_amdgcn_mfma_f32_16x16x32_bf16(a0, bx[c][0], acc[0][0], 0, 0, 0);
            acc[1][0] = __builtin_amdgcn_mfma_f32_16x16x32_bf16(a1, bx[c][0], acc[1][0], 0, 0, 0);
            acc[2][0] = __builtin_amdgcn_mfma_f32_16x16x32_bf16(a2, bx[c][0], acc[2][0], 0, 0, 0);
            acc[3][0] = __builtin_amdgcn_mfma_f32_16x16x32_bf16(a3, bx[c][0], acc[3][0], 0, 0, 0);
            acc[0][1] = __builtin_amdgcn_mfma_f32_16x16x32_bf16(a0, bx[c][1], acc[0][1], 0, 0, 0);
            acc[1][1] = __builtin_amdgcn_mfma_f32_16x16x32_bf16(a1, bx[c][1], acc[1][1], 0, 0, 0);
            acc[2][1] = __builtin_amdgcn_mfma_f32_16x16x32_bf16(a2, bx[c][1], acc[2][1], 0, 0, 0);
            acc[3][1] = __builtin_amdgcn_mfma_f32_16x16x32_bf16(a3, bx[c][1], acc[3][1], 0, 0, 0);
        }
    }

    for (int t = 0; t < Tn; ++t) {
        // ---- h-part (gated on this wave's step t-1 producer poll) ----
        // depth-2 ring: chunk c+1 issued under chunk c's MFMAs (proven R6)
        const unsigned short* hrow = h_all + (size_t)t * (Bn * Hn)
                                   + (size_t)(m0 + lr) * Hn + w * 256 + quad * 8;
        s8v A[2][4];
        #pragma unroll
        for (int r = 0; r < 4; ++r)
            A[0][r] = *(const s8v*)(hrow + hoff * 32 + r * 16 * Hn);
        #pragma unroll
        for (int c = 0; c < 8; ++c) {
            if (c < 7) {
                const unsigned short* p = hrow + ((c + 1 + hoff) & 7) * 32;
                #pragma unroll
                for (int r = 0; r < 4; ++r)
                    A[(c + 1) & 1][r] = *(const s8v*)(p + r * 16 * Hn);
            }
            const s8v a0 = A[c & 1][0];
            const s8v a1 = A[c & 1][1];
            const s8v a2 = A[c & 1][2];
            const s8v a3 = A[c & 1][3];
            acc[0][0] = __builtin_amdgcn_mfma_f32_16x16x32_bf16(a0, bh[c][0], acc[0][0], 0, 0, 0);
            acc[1][0] = __builtin_amdgcn_mfma_f32_16x16x32_bf16(a1, bh[c][0], acc[1][0], 0, 0, 0);
            acc[2][0] = __builtin_amdgcn_mfma_f32_16x16x32_bf16(a2, bh[c][0], acc[2][0], 0, 0, 0);
            acc[3][0] = __builtin_amdgcn_mfma_f32_16x16x32_bf16(a3, bh[c][0], acc[3][0], 0, 0, 0);
            acc[0][1] = __builtin_amdgcn_mfma_f32_16x16x32_bf16(a0, bh[c][1], acc[0][1], 0, 0, 0);
            acc[1][1] = __builtin_amdgcn_mfma_f32_16x16x32_bf16(a1, bh[c][1], acc[1][1], 0, 0, 0);
            acc[2][1] = __builtin_amdgcn_mfma_f32_16x16x32_bf16(a2, bh[c][1], acc[2][1], 0, 0, 0);
            acc[3][1] = __builtin_amdgcn_mfma_f32_16x16x32_bf16(a3, bh[c][1], acc[3][1], 0, 0, 0);
        }

        // ---- LDS reduce write: C/D layout row=quad*4+reg, col=lane&15 ----
        #pragma unroll
        for (int mi = 0; mi < 4; ++mi)
            #pragma unroll
            for (int ni = 0; ni < 2; ++ni)
                #pragma unroll
                for (int rr = 0; rr < 4; ++rr)
                    red[w][mi * 16 + quad * 4 + rr][ni * 16 + lr] = acc[mi][ni][rr];

        // ---- x-prefetch (2 of 4 chunks) for t+1: flies under the reduce ----
        s8v X[2][4];
        const unsigned short* arn = xb + (size_t)(t + 1) * In
                                  + (size_t)(m0 + lr) * xrow + w * 128 + quad * 8;
        if (t < Tn - 1) {
            #pragma unroll
            for (int c = 0; c < 2; ++c) {
                const unsigned short* p = arn + ((c + xoff) & 3) * 32;
                #pragma unroll
                for (int r = 0; r < 4; ++r)
                    X[c][r] = *(const s8v*)(p + r * 16 * xrow);
            }
        }

        // sync1: LDS-only barrier (NO vmcnt drain -> X stays in flight)
        __builtin_amdgcn_sched_barrier(0);
        asm volatile("s_waitcnt lgkmcnt(0)" ::: "memory");
        __builtin_amdgcn_s_barrier();
        __builtin_amdgcn_sched_barrier(0);

        {   // final reduce + tanh + agent-scope write-through store (8 B)
            int j = threadIdx.x << 2;
            int row = j >> 5;
            int c0 = j & 31;
            float4 s0 = *(const float4*)&red[0][row][c0];
            float4 s1 = *(const float4*)&red[1][row][c0];
            float4 s2 = *(const float4*)&red[2][row][c0];
            float4 s3 = *(const float4*)&red[3][row][c0];
            float4 s4 = *(const float4*)&red[4][row][c0];
            float4 s5 = *(const float4*)&red[5][row][c0];
            float4 s6 = *(const float4*)&red[6][row][c0];
            float4 s7 = *(const float4*)&red[7][row][c0];
            us4 o4;
            o4[0] = f2bf(fast_tanh(((s0.x + s1.x) + (s2.x + s3.x)) + ((s4.x + s5.x) + (s6.x + s7.x))));
            o4[1] = f2bf(fast_tanh(((s0.y + s1.y) + (s2.y + s3.y)) + ((s4.y + s5.y) + (s6.y + s7.y))));
            o4[2] = f2bf(fast_tanh(((s0.z + s1.z) + (s2.z + s3.z)) + ((s4.z + s5.z) + (s6.z + s7.z))));
            o4[3] = f2bf(fast_tanh(((s0.w + s1.w) + (s2.w + s3.w)) + ((s4.w + s5.w) + (s6.w + s7.w))));
            unsigned long long* dst = (unsigned long long*)
                (h_all + (size_t)(t + 1) * (Bn * Hn) + (size_t)(m0 + row) * Hn + n0 + c0);
            __hip_atomic_store(dst, __builtin_bit_cast(unsigned long long, o4),
                               __ATOMIC_RELAXED, __HIP_MEMORY_SCOPE_AGENT);
        }

        if (t < Tn - 1) {
            __syncthreads();                             // sync2: vmcnt(0) drain (h store + X done)
            const unsigned int tp1 = (unsigned int)(t + 1);

            // ---- ARRIVE: one contention-free flag store ----
            if (threadIdx.x == 0)
                __hip_atomic_store(bar + fidx, tp1, __ATOMIC_RELAXED,
                                   __HIP_MEMORY_SCOPE_AGENT);

            // ---- x-part of t+1: chunks 0,1 from prefetch; 2,3 load now ----
            #pragma unroll
            for (int mi = 0; mi < 4; ++mi)
                #pragma unroll
                for (int ni = 0; ni < 2; ++ni)
                    acc[mi][ni] = (f32x4){0.f, 0.f, 0.f, 0.f};
            #pragma unroll
            for (int c = 0; c < 2; ++c) {
                acc[0][0] = __builtin_amdgcn_mfma_f32_16x16x32_bf16(X[c][0], bx[c][0], acc[0][0], 0, 0, 0);
                acc[1][0] = __builtin_amdgcn_mfma_f32_16x16x32_bf16(X[c][1], bx[c][0], acc[1][0], 0, 0, 0);
                acc[2][0] = __builtin_amdgcn_mfma_f32_16x16x32_bf16(X[c][2], bx[c][0], acc[2][0], 0, 0, 0);
                acc[3][0] = __builtin_amdgcn_mfma_f32_16x16x32_bf16(X[c][3], bx[c][0], acc[3][0], 0, 0, 0);
                acc[0][1] = __builtin_amdgcn_mfma_f32_16x16x32_bf16(X[c][0], bx[c][1], acc[0][1], 0, 0, 0);
                acc[1][1] = __builtin_amdgcn_mfma_f32_16x16x32_bf16(X[c][1], bx[c][1], acc[1][1], 0, 0, 0);
                acc[2][1] = __builtin_amdgcn_mfma_f32_16x16x32_bf16(X[c][2], bx[c][1], acc[2][1], 0, 0, 0);
                acc[3][1] = __builtin_amdgcn_mfma_f32_16x16x32_bf16(X[c][3], bx[c][1], acc[3][1], 0, 0, 0);
            }
            #pragma unroll
            for (int c = 2; c < 4; ++c) {
                const unsigned short* p = arn + ((c + xoff) & 3) * 32;
                s8v a0 = *(const s8v*)(p);
                s8v a1 = *(const s8v*)(p + 16 * xrow);
                s8v a2 = *(const s8v*)(p + 32 * xrow);
                s8v a3 = *(const s8v*)(p + 48 * xrow);
                acc[0][0] = __builtin_amdgcn_mfma_f32_16x16x32_bf16(a0, bx[c][0], acc[0][0], 0, 0, 0);
                acc[1][0] = __builtin_amdgcn_mfma_f32_16x16x32_bf16(a1, bx[c][0], acc[1][0], 0, 0, 0);
                acc[2][0] = __builtin_amdgcn_mfma_f32_16x16x32_bf16(a2, bx[c][0], acc[2][0], 0, 0, 0);
                acc[3][0] = __builtin_amdgcn_mfma_f32_16x16x32_bf16(a3, bx[c][0], acc[3][0], 0, 0, 0);
                acc[0][1] = __builtin_amdgcn_mfma_f32_16x16x32_bf16(a0, bx[c][1], acc[0][1], 0, 0, 0);
                acc[1][1] = __builtin_amdgcn_mfma_f32_16x16x32_bf16(a1, bx[c][1], acc[1][1], 0, 0, 0);
                acc[2][1] = __builtin_amdgcn_mfma_f32_16x16x32_bf16(a2, bx[c][1], acc[2][1], 0, 0, 0);
                acc[3][1] = __builtin_amdgcn_mfma_f32_16x16x32_bf16(a3, bx[c][1], acc[3][1], 0, 0, 0);
            }

            // ---- PER-WAVE producer poll: wave w needs only blocks
            // nIdx in [w*8, w*8+8) (its h k-slice's producers). No release
            // barrier: each wave proceeds the moment ITS producers are
            // visible; block re-converges at sync1 of the next step.
            {
                unsigned int* pf = fl + w * 8 + (lane & 7);
                while (true) {
                    unsigned int v = __hip_atomic_load(pf, __ATOMIC_RELAXED,
                                                       __HIP_MEMORY_SCOPE_AGENT);
                    if (__all((int)(v >= tp1))) break;
                    __builtin_amdgcn_s_sleep(1);
                }
            }
            asm volatile("" ::: "memory");               // no load hoisting above the poll
        }
    }
}

// ---- output projection ---------------------------------------------------
// y[b][t][o] = h_all[t+1][b][:] . lin_w[o][:] + lin_b[o]. One 16-row wave per 16 (t,b) rows.
__global__ __launch_bounds__(256)
void gemm2_kernel(const unsigned short* __restrict__ h_all, const unsigned short* __restrict__ lwb,
                  const float* __restrict__ lb, float* __restrict__ y) {
    int gw = blockIdx.x * 4 + (threadIdx.x >> 6);       // 0..1599
    int lane = threadIdx.x & 63, quad = lane >> 4, lr = lane & 15;
    int m0 = gw * 16;
    int t = m0 >> 8;
    int b0 = m0 & 255;
    const unsigned short* ah = h_all + ((size_t)(t + 1) * Bn + b0 + lr) * Hn + quad * 8;
    const unsigned short* bh = lwb + (size_t)lr * Hn + quad * 8;
    f32x4 acc0 = {0.f, 0.f, 0.f, 0.f}, acc1 = {0.f, 0.f, 0.f, 0.f};
    #pragma unroll
    for (int k0 = 0; k0 < Hn; k0 += 64) {
        s8v a0 = *(const s8v*)(ah + k0);
        s8v b0 = *(const s8v*)(bh + k0);
        acc0 = __builtin_amdgcn_mfma_f32_16x16x32_bf16(a0, b0, acc0, 0, 0, 0);
        s8v a1 = *(const s8v*)(ah + k0 + 32);
        s8v b1 = *(const s8v*)(bh + k0 + 32);
        acc1 = __builtin_amdgcn_mfma_f32_16x16x32_bf16(a1, b1, acc1, 0, 0, 0);
    }
    acc0 = acc0 + acc1;
    if (lr < On) {
        float bias = lb[lr];
        #pragma unroll
        for (int rr = 0; rr < 4; ++rr) {
            int b = b0 + quad * 4 + rr;
            y[(size_t)b * (Tn * On) + t * On + lr] = acc0[rr] + bias;
        }
    }
}

// ---- host ----------------------------------------------------------------

extern "C" void kernel_launch(void* const* d_in, const int* in_sizes, int n_in,
                              void* d_out, int out_size, void* d_ws, size_t ws_size,
                              hipStream_t stream) {
    const float* x   = (const float*)d_in[0];
    const float* h0  = (const float*)d_in[1];
    const float* Win = (const float*)d_in[2];
    const float* W   = (const float*)d_in[3];
    const float* lw  = (const float*)d_in[4];
    const float* lb  = (const float*)d_in[5];
    float* y = (float*)d_out;

    // ws layout (bf16 elems): ~171 MB total
    unsigned short* ws    = (unsigned short*)d_ws;
    unsigned short* xb    = ws;                                  // 26,214,400 elems
    unsigned short* BTm   = xb + (size_t)Bn * Tn * In;           //  6,291,456 elems [2048][3072]
    unsigned short* h_all = BTm + (size_t)Hn * Kc;               // 52,953,088 elems [(T+1)][B][H]
    unsigned short* lwb   = h_all + (size_t)(Tn + 1) * Bn * Hn;  //     32,768 elems [16][2048]
    unsigned int*   bar   = (unsigned int*)(lwb + 32768);        // 512 uints flag block

    conv_x_kernel<<<25600, 256, 0, stream>>>((const float4*)x, (ushort4*)xb);
    transpose_bf16_kernel<<<dim3(32, 64), 256, 0, stream>>>(Win, BTm, Hn, Kc, 0);
    transpose_bf16_kernel<<<dim3(64, 64), 256, 0, stream>>>(W, BTm, Hn, Kc, In);
    small_conv_kernel<<<2176, 256, 0, stream>>>(h0, lw, h_all, lwb, bar);

    scan_kernel<<<256, 512, 0, stream>>>(xb, BTm, h_all, bar);

    gemm2_kernel<<<400, 256, 0, stream>>>(h_all, lwb, lb, y);
}

// Round 10
// 1307.355 us; speedup vs baseline: 1.1317x; 1.0038x over previous
//
#include <hip/hip_runtime.h>
#include <math.h>

// Problem constants
#define Bn 256
#define Tn 100
#define In 1024
#define Hn 2048
#define On 10
#define Kc (In + Hn)   // 3072 concatenated K

typedef short s8v  __attribute__((ext_vector_type(8)));   // 8 x bf16 (as raw shorts), 4 VGPRs
typedef unsigned short us4 __attribute__((ext_vector_type(4)));
typedef float f32x4 __attribute__((ext_vector_type(4)));

__device__ __forceinline__ unsigned short f2bf(float f) {
    unsigned int u = __float_as_uint(f);
    u += 0x7fffu + ((u >> 16) & 1u);   // round-to-nearest-even
    return (unsigned short)(u >> 16);
}

// Branch-free exact tanh: 1 - 2/(exp(2x)+1). ~1e-6 abs err, under bf16 rounding.
__device__ __forceinline__ float fast_tanh(float x) {
    float e = __expf(x + x);
    return 1.0f - 2.0f * __builtin_amdgcn_rcpf(e + 1.0f);
}

// ---- setup kernels -------------------------------------------------------

// x [B][T][I] fp32 -> bf16, 4 elems/thread
__global__ void conv_x_kernel(const float4* __restrict__ src, ushort4* __restrict__ dst) {
    int i = blockIdx.x * 256 + threadIdx.x;
    float4 v = src[i];
    ushort4 o;
    o.x = f2bf(v.x); o.y = f2bf(v.y); o.z = f2bf(v.z); o.w = f2bf(v.w);
    dst[i] = o;
}

// src [K][N=2048] fp32 -> dst[n][colOff + k] bf16  (builds B^T = [Win;W]^T rows)
__global__ void transpose_bf16_kernel(const float* __restrict__ src, unsigned short* __restrict__ dst,
                                      int N, int ld, int colOff) {
    __shared__ float tile[32][33];
    int k0 = blockIdx.x * 32;
    int n0 = blockIdx.y * 32;
    int c = threadIdx.x & 31;
    int r = threadIdx.x >> 5;            // 0..7
    #pragma unroll
    for (int i = 0; i < 32; i += 8)
        tile[r + i][c] = src[(size_t)(k0 + r + i) * N + n0 + c];
    __syncthreads();
    #pragma unroll
    for (int i = 0; i < 32; i += 8)
        dst[(size_t)(n0 + r + i) * ld + colOff + k0 + c] = f2bf(tile[c][r + i]);
}

// h0 -> h_all slot 0 (bf16); lin_w -> padded bf16 [16][2048]; zero barrier block
__global__ void small_conv_kernel(const float* __restrict__ h0, const float* __restrict__ lin_w,
                                  unsigned short* __restrict__ h_all0, unsigned short* __restrict__ lwb,
                                  unsigned int* __restrict__ bar) {
    int idx = blockIdx.x * 256 + threadIdx.x;
    if (idx < 512) bar[idx] = 0u;        // per-block flags (re-zeroed every launch)
    if (idx < Bn * Hn) {
        h_all0[idx] = f2bf(h0[idx]);
    } else {
        int j = idx - Bn * Hn;           // < 16*2048 exactly (grid sized for it)
        int o = j >> 11;
        int k = j & 2047;
        lwb[j] = (o < On) ? f2bf(lin_w[o * Hn + k]) : (unsigned short)0;
    }
}

// ---- persistent scan -----------------------------------------------------
// R14 = R13 with the FLAG-INDEX BUG FIXED.
// R13 post-mortem: absmax 0.015625 -> 0.046875 with bit-identical arithmetic
// = stale reads. Root cause: flag slot ((g&1)*32+(g>>3)) and n-position
// (nIdx=(g>>3)*2+(g&1)) are DIFFERENT bijections of 0..63. Wave w polled
// slots [w*8,+8) believing they were producers nIdx in [w*8,+8) -> polled
// the WRONG producers -> raced ahead. R10 was immune (w0 polled all 64).
// Fix: flag slot = nIdx directly (fidx = mg*64 + nIdx). Per-wave producer
// poll is now correct: wave w's h k-slice [w*256,+256) is produced exactly
// by blocks nIdx in [w*8, w*8+8) = flag slots [w*8, w*8+8).
//  * LDS-safe (unchanged): all red reads complete before sync2 (barrier);
//    each wave writes only red[w] after sync2; block re-converges at sync1.
// Sync (proven R4-R10): relaxed agent-scope write-through h stores;
// __syncthreads (sync2) drains vmcnt(0) before the flag store; fresh h
// addresses each step make plain consumer loads safe.
__global__ __launch_bounds__(512, 2)
void scan_kernel(const unsigned short* __restrict__ xb,
                 const unsigned short* __restrict__ BTm,
                 unsigned short* __restrict__ h_all,
                 unsigned int* __restrict__ bar) {
    const int g = blockIdx.x;
    const int mg = (g & 7) >> 1;                        // m-group = XCD pair
    const int m0 = mg * 64;
    const int nIdx = (g >> 3) * 2 + (g & 1);            // 0..63 within group
    const int n0 = nIdx * 32;
    const int w = threadIdx.x >> 6;                     // 0..7
    const int lane = threadIdx.x & 63;
    const int quad = lane >> 4;
    const int lr = lane & 15;
    const int hoff = nIdx & 7;                          // h k-rotation
    const int xoff = nIdx & 3;                          // x k-rotation

    __shared__ float red[8][64][36];                    // pad 36: 2-way banks (free)

    const unsigned short* bp0 = BTm + (size_t)(n0 + lr) * Kc;
    const unsigned short* bp1 = BTm + (size_t)(n0 + 16 + lr) * Kc;

    const size_t xrow = (size_t)Tn * In;                // x row stride (102400)

    // flag layout: bar[mg*64 + nIdx]  (nIdx-DIRECT: slot == producer n-pos)
    const int fidx = mg * 64 + nIdx;
    unsigned int* fl = bar + mg * 64;                   // my group's 64 flags

    // ---- one-time B-fragment preload, PRE-ROTATED by hoff/xoff ----
    s8v bx[4][2];                                       // bx[c] = x-chunk (c+xoff)&3
    s8v bh[8][2];                                       // bh[c] = h-chunk (c+hoff)&7
    #pragma unroll
    for (int c = 0; c < 4; ++c) {
        const int kq = w * 128 + (((c + xoff) & 3) * 32) + quad * 8;
        bx[c][0] = *(const s8v*)(bp0 + kq);
        bx[c][1] = *(const s8v*)(bp1 + kq);
    }
    #pragma unroll
    for (int c = 0; c < 8; ++c) {
        const int kq = In + w * 256 + (((c + hoff) & 7) * 32) + quad * 8;
        bh[c][0] = *(const s8v*)(bp0 + kq);
        bh[c][1] = *(const s8v*)(bp1 + kq);
    }

    f32x4 acc[4][2];
    #pragma unroll
    for (int mi = 0; mi < 4; ++mi)
        #pragma unroll
        for (int ni = 0; ni < 2; ++ni)
            acc[mi][ni] = (f32x4){0.f, 0.f, 0.f, 0.f};

    // ---- x-part for t=0 (rotated chunk order) ----
    {
        const unsigned short* ar0 = xb + (size_t)(m0 + lr) * xrow + w * 128 + quad * 8;
        #pragma unroll
        for (int c = 0; c < 4; ++c) {
            const unsigned short* arow = ar0 + ((c + xoff) & 3) * 32;
            s8v a0 = *(const s8v*)(arow);
            s8v a1 = *(const s8v*)(arow + 16 * xrow);
            s8v a2 = *(const s8v*)(arow + 32 * xrow);
            s8v a3 = *(const s8v*)(arow + 48 * xrow);
            acc[0][0] = __builtin_amdgcn_mfma_f32_16x16x32_bf16(a0, bx[c][0], acc[0][0], 0, 0, 0);
            acc[1][0] = __builtin_amdgcn_mfma_f32_16x16x32_bf16(a1, bx[c][0], acc[1][0], 0, 0, 0);
            acc[2][0] = __builtin_amdgcn_mfma_f32_16x16x32_bf16(a2, bx[c][0], acc[2][0], 0, 0, 0);
            acc[3][0] = __builtin_amdgcn_mfma_f32_16x16x32_bf16(a3, bx[c][0], acc[3][0], 0, 0, 0);
            acc[0][1] = __builtin_amdgcn_mfma_f32_16x16x32_bf16(a0, bx[c][1], acc[0][1], 0, 0, 0);
            acc[1][1] = __builtin_amdgcn_mfma_f32_16x16x32_bf16(a1, bx[c][1], acc[1][1], 0, 0, 0);
            acc[2][1] = __builtin_amdgcn_mfma_f32_16x16x32_bf16(a2, bx[c][1], acc[2][1], 0, 0, 0);
            acc[3][1] = __builtin_amdgcn_mfma_f32_16x16x32_bf16(a3, bx[c][1], acc[3][1], 0, 0, 0);
        }
    }

    for (int t = 0; t < Tn; ++t) {
        // ---- h-part (gated on this wave's step t-1 producer poll) ----
        // depth-2 ring: chunk c+1 issued under chunk c's MFMAs (proven R6)
        const unsigned short* hrow = h_all + (size_t)t * (Bn * Hn)
                                   + (size_t)(m0 + lr) * Hn + w * 256 + quad * 8;
        s8v A[2][4];
        #pragma unroll
        for (int r = 0; r < 4; ++r)
            A[0][r] = *(const s8v*)(hrow + hoff * 32 + r * 16 * Hn);
        #pragma unroll
        for (int c = 0; c < 8; ++c) {
            if (c < 7) {
                const unsigned short* p = hrow + ((c + 1 + hoff) & 7) * 32;
                #pragma unroll
                for (int r = 0; r < 4; ++r)
                    A[(c + 1) & 1][r] = *(const s8v*)(p + r * 16 * Hn);
            }
            const s8v a0 = A[c & 1][0];
            const s8v a1 = A[c & 1][1];
            const s8v a2 = A[c & 1][2];
            const s8v a3 = A[c & 1][3];
            acc[0][0] = __builtin_amdgcn_mfma_f32_16x16x32_bf16(a0, bh[c][0], acc[0][0], 0, 0, 0);
            acc[1][0] = __builtin_amdgcn_mfma_f32_16x16x32_bf16(a1, bh[c][0], acc[1][0], 0, 0, 0);
            acc[2][0] = __builtin_amdgcn_mfma_f32_16x16x32_bf16(a2, bh[c][0], acc[2][0], 0, 0, 0);
            acc[3][0] = __builtin_amdgcn_mfma_f32_16x16x32_bf16(a3, bh[c][0], acc[3][0], 0, 0, 0);
            acc[0][1] = __builtin_amdgcn_mfma_f32_16x16x32_bf16(a0, bh[c][1], acc[0][1], 0, 0, 0);
            acc[1][1] = __builtin_amdgcn_mfma_f32_16x16x32_bf16(a1, bh[c][1], acc[1][1], 0, 0, 0);
            acc[2][1] = __builtin_amdgcn_mfma_f32_16x16x32_bf16(a2, bh[c][1], acc[2][1], 0, 0, 0);
            acc[3][1] = __builtin_amdgcn_mfma_f32_16x16x32_bf16(a3, bh[c][1], acc[3][1], 0, 0, 0);
        }

        // ---- LDS reduce write: C/D layout row=quad*4+reg, col=lane&15 ----
        #pragma unroll
        for (int mi = 0; mi < 4; ++mi)
            #pragma unroll
            for (int ni = 0; ni < 2; ++ni)
                #pragma unroll
                for (int rr = 0; rr < 4; ++rr)
                    red[w][mi * 16 + quad * 4 + rr][ni * 16 + lr] = acc[mi][ni][rr];

        // ---- x-prefetch (2 of 4 chunks) for t+1: flies under the reduce ----
        s8v X[2][4];
        const unsigned short* arn = xb + (size_t)(t + 1) * In
                                  + (size_t)(m0 + lr) * xrow + w * 128 + quad * 8;
        if (t < Tn - 1) {
            #pragma unroll
            for (int c = 0; c < 2; ++c) {
                const unsigned short* p = arn + ((c + xoff) & 3) * 32;
                #pragma unroll
                for (int r = 0; r < 4; ++r)
                    X[c][r] = *(const s8v*)(p + r * 16 * xrow);
            }
        }

        // sync1: LDS-only barrier (NO vmcnt drain -> X stays in flight)
        __builtin_amdgcn_sched_barrier(0);
        asm volatile("s_waitcnt lgkmcnt(0)" ::: "memory");
        __builtin_amdgcn_s_barrier();
        __builtin_amdgcn_sched_barrier(0);

        {   // final reduce + tanh + agent-scope write-through store (8 B)
            int j = threadIdx.x << 2;
            int row = j >> 5;
            int c0 = j & 31;
            float4 s0 = *(const float4*)&red[0][row][c0];
            float4 s1 = *(const float4*)&red[1][row][c0];
            float4 s2 = *(const float4*)&red[2][row][c0];
            float4 s3 = *(const float4*)&red[3][row][c0];
            float4 s4 = *(const float4*)&red[4][row][c0];
            float4 s5 = *(const float4*)&red[5][row][c0];
            float4 s6 = *(const float4*)&red[6][row][c0];
            float4 s7 = *(const float4*)&red[7][row][c0];
            us4 o4;
            o4[0] = f2bf(fast_tanh(((s0.x + s1.x) + (s2.x + s3.x)) + ((s4.x + s5.x) + (s6.x + s7.x))));
            o4[1] = f2bf(fast_tanh(((s0.y + s1.y) + (s2.y + s3.y)) + ((s4.y + s5.y) + (s6.y + s7.y))));
            o4[2] = f2bf(fast_tanh(((s0.z + s1.z) + (s2.z + s3.z)) + ((s4.z + s5.z) + (s6.z + s7.z))));
            o4[3] = f2bf(fast_tanh(((s0.w + s1.w) + (s2.w + s3.w)) + ((s4.w + s5.w) + (s6.w + s7.w))));
            unsigned long long* dst = (unsigned long long*)
                (h_all + (size_t)(t + 1) * (Bn * Hn) + (size_t)(m0 + row) * Hn + n0 + c0);
            __hip_atomic_store(dst, __builtin_bit_cast(unsigned long long, o4),
                               __ATOMIC_RELAXED, __HIP_MEMORY_SCOPE_AGENT);
        }

        if (t < Tn - 1) {
            __syncthreads();                             // sync2: vmcnt(0) drain (h store + X done)
            const unsigned int tp1 = (unsigned int)(t + 1);

            // ---- ARRIVE: one contention-free flag store (slot == nIdx) ----
            if (threadIdx.x == 0)
                __hip_atomic_store(bar + fidx, tp1, __ATOMIC_RELAXED,
                                   __HIP_MEMORY_SCOPE_AGENT);

            // ---- x-part of t+1: chunks 0,1 from prefetch; 2,3 load now ----
            #pragma unroll
            for (int mi = 0; mi < 4; ++mi)
                #pragma unroll
                for (int ni = 0; ni < 2; ++ni)
                    acc[mi][ni] = (f32x4){0.f, 0.f, 0.f, 0.f};
            #pragma unroll
            for (int c = 0; c < 2; ++c) {
                acc[0][0] = __builtin_amdgcn_mfma_f32_16x16x32_bf16(X[c][0], bx[c][0], acc[0][0], 0, 0, 0);
                acc[1][0] = __builtin_amdgcn_mfma_f32_16x16x32_bf16(X[c][1], bx[c][0], acc[1][0], 0, 0, 0);
                acc[2][0] = __builtin_amdgcn_mfma_f32_16x16x32_bf16(X[c][2], bx[c][0], acc[2][0], 0, 0, 0);
                acc[3][0] = __builtin_amdgcn_mfma_f32_16x16x32_bf16(X[c][3], bx[c][0], acc[3][0], 0, 0, 0);
                acc[0][1] = __builtin_amdgcn_mfma_f32_16x16x32_bf16(X[c][0], bx[c][1], acc[0][1], 0, 0, 0);
                acc[1][1] = __builtin_amdgcn_mfma_f32_16x16x32_bf16(X[c][1], bx[c][1], acc[1][1], 0, 0, 0);
                acc[2][1] = __builtin_amdgcn_mfma_f32_16x16x32_bf16(X[c][2], bx[c][1], acc[2][1], 0, 0, 0);
                acc[3][1] = __builtin_amdgcn_mfma_f32_16x16x32_bf16(X[c][3], bx[c][1], acc[3][1], 0, 0, 0);
            }
            #pragma unroll
            for (int c = 2; c < 4; ++c) {
                const unsigned short* p = arn + ((c + xoff) & 3) * 32;
                s8v a0 = *(const s8v*)(p);
                s8v a1 = *(const s8v*)(p + 16 * xrow);
                s8v a2 = *(const s8v*)(p + 32 * xrow);
                s8v a3 = *(const s8v*)(p + 48 * xrow);
                acc[0][0] = __builtin_amdgcn_mfma_f32_16x16x32_bf16(a0, bx[c][0], acc[0][0], 0, 0, 0);
                acc[1][0] = __builtin_amdgcn_mfma_f32_16x16x32_bf16(a1, bx[c][0], acc[1][0], 0, 0, 0);
                acc[2][0] = __builtin_amdgcn_mfma_f32_16x16x32_bf16(a2, bx[c][0], acc[2][0], 0, 0, 0);
                acc[3][0] = __builtin_amdgcn_mfma_f32_16x16x32_bf16(a3, bx[c][0], acc[3][0], 0, 0, 0);
                acc[0][1] = __builtin_amdgcn_mfma_f32_16x16x32_bf16(a0, bx[c][1], acc[0][1], 0, 0, 0);
                acc[1][1] = __builtin_amdgcn_mfma_f32_16x16x32_bf16(a1, bx[c][1], acc[1][1], 0, 0, 0);
                acc[2][1] = __builtin_amdgcn_mfma_f32_16x16x32_bf16(a2, bx[c][1], acc[2][1], 0, 0, 0);
                acc[3][1] = __builtin_amdgcn_mfma_f32_16x16x32_bf16(a3, bx[c][1], acc[3][1], 0, 0, 0);
            }

            // ---- PER-WAVE producer poll (now with CORRECT slots): wave w
            // needs blocks nIdx in [w*8, w*8+8) == flag slots [w*8, w*8+8).
            // No release barrier: each wave proceeds when ITS producers are
            // visible; block re-converges at sync1 of the next step.
            {
                unsigned int* pf = fl + w * 8 + (lane & 7);
                while (true) {
                    unsigned int v = __hip_atomic_load(pf, __ATOMIC_RELAXED,
                                                       __HIP_MEMORY_SCOPE_AGENT);
                    if (__all((int)(v >= tp1))) break;
                    __builtin_amdgcn_s_sleep(1);
                }
            }
            asm volatile("" ::: "memory");               // no load hoisting above the poll
        }
    }
}

// ---- output projection ---------------------------------------------------
// y[b][t][o] = h_all[t+1][b][:] . lin_w[o][:] + lin_b[o]. One 16-row wave per 16 (t,b) rows.
__global__ __launch_bounds__(256)
void gemm2_kernel(const unsigned short* __restrict__ h_all, const unsigned short* __restrict__ lwb,
                  const float* __restrict__ lb, float* __restrict__ y) {
    int gw = blockIdx.x * 4 + (threadIdx.x >> 6);       // 0..1599
    int lane = threadIdx.x & 63, quad = lane >> 4, lr = lane & 15;
    int m0 = gw * 16;
    int t = m0 >> 8;
    int b0 = m0 & 255;
    const unsigned short* ah = h_all + ((size_t)(t + 1) * Bn + b0 + lr) * Hn + quad * 8;
    const unsigned short* bh = lwb + (size_t)lr * Hn + quad * 8;
    f32x4 acc0 = {0.f, 0.f, 0.f, 0.f}, acc1 = {0.f, 0.f, 0.f, 0.f};
    #pragma unroll
    for (int k0 = 0; k0 < Hn; k0 += 64) {
        s8v a0 = *(const s8v*)(ah + k0);
        s8v b0 = *(const s8v*)(bh + k0);
        acc0 = __builtin_amdgcn_mfma_f32_16x16x32_bf16(a0, b0, acc0, 0, 0, 0);
        s8v a1 = *(const s8v*)(ah + k0 + 32);
        s8v b1 = *(const s8v*)(bh + k0 + 32);
        acc1 = __builtin_amdgcn_mfma_f32_16x16x32_bf16(a1, b1, acc1, 0, 0, 0);
    }
    acc0 = acc0 + acc1;
    if (lr < On) {
        float bias = lb[lr];
        #pragma unroll
        for (int rr = 0; rr < 4; ++rr) {
            int b = b0 + quad * 4 + rr;
            y[(size_t)b * (Tn * On) + t * On + lr] = acc0[rr] + bias;
        }
    }
}

// ---- host ----------------------------------------------------------------

extern "C" void kernel_launch(void* const* d_in, const int* in_sizes, int n_in,
                              void* d_out, int out_size, void* d_ws, size_t ws_size,
                              hipStream_t stream) {
    const float* x   = (const float*)d_in[0];
    const float* h0  = (const float*)d_in[1];
    const float* Win = (const float*)d_in[2];
    const float* W   = (const float*)d_in[3];
    const float* lw  = (const float*)d_in[4];
    const float* lb  = (const float*)d_in[5];
    float* y = (float*)d_out;

    // ws layout (bf16 elems): ~171 MB total
    unsigned short* ws    = (unsigned short*)d_ws;
    unsigned short* xb    = ws;                                  // 26,214,400 elems
    unsigned short* BTm   = xb + (size_t)Bn * Tn * In;           //  6,291,456 elems [2048][3072]
    unsigned short* h_all = BTm + (size_t)Hn * Kc;               // 52,953,088 elems [(T+1)][B][H]
    unsigned short* lwb   = h_all + (size_t)(Tn + 1) * Bn * Hn;  //     32,768 elems [16][2048]
    unsigned int*   bar   = (unsigned int*)(lwb + 32768);        // 512 uints flag block

    conv_x_kernel<<<25600, 256, 0, stream>>>((const float4*)x, (ushort4*)xb);
    transpose_bf16_kernel<<<dim3(32, 64), 256, 0, stream>>>(Win, BTm, Hn, Kc, 0);
    transpose_bf16_kernel<<<dim3(64, 64), 256, 0, stream>>>(W, BTm, Hn, Kc, In);
    small_conv_kernel<<<2176, 256, 0, stream>>>(h0, lw, h_all, lwb, bar);

    scan_kernel<<<256, 512, 0, stream>>>(xb, BTm, h_all, bar);

    gemm2_kernel<<<400, 256, 0, stream>>>(h_all, lwb, lb, y);
}